// Round 1
// baseline (1453.048 us; speedup 1.0000x reference)
//
#include <hip/hip_runtime.h>
#include <hip/hip_fp16.h>
#include <cstdint>
#include <cstddef>

typedef _Float16 f16x8 __attribute__((ext_vector_type(8)));
typedef _Float16 f16x4 __attribute__((ext_vector_type(4)));
typedef float    f32x4 __attribute__((ext_vector_type(4)));

__device__ __forceinline__ float sigmoidf_(float x) { return 1.f / (1.f + __expf(-x)); }

// ---------------- cast f32 -> f16 (n4 = n/4 float4 groups) ----------------
__global__ __launch_bounds__(256) void k_cast16(const float* __restrict__ src,
                                                _Float16* __restrict__ dst, int n4) {
  int i = blockIdx.x * 256 + threadIdx.x;
  if (i < n4) {
    float4 v = ((const float4*)src)[i];
    f16x4 o = {(_Float16)v.x, (_Float16)v.y, (_Float16)v.z, (_Float16)v.w};
    ((f16x4*)dst)[i] = o;
  }
}

// ------- transpose + cast: src (R x C) f32 -> dst (Cpad x R) f16, zero pad -------
__global__ void k_transpose16(const float* __restrict__ src, _Float16* __restrict__ dst,
                              int R, int C, int Cpad) {
  __shared__ float tile[32][33];
  int c0 = blockIdx.x * 32, r0 = blockIdx.y * 32;
  int tx = threadIdx.x, ty = threadIdx.y;  // 32 x 8
  #pragma unroll
  for (int i = 0; i < 32; i += 8) {
    int r = r0 + ty + i, c = c0 + tx;
    tile[ty + i][tx] = (r < R && c < C) ? src[(size_t)r * C + c] : 0.f;
  }
  __syncthreads();
  #pragma unroll
  for (int i = 0; i < 32; i += 8) {
    int cc = c0 + ty + i, rr = r0 + tx;
    if (cc < Cpad && rr < R) dst[(size_t)cc * R + rr] = (_Float16)tile[tx][ty + i];
  }
}

// ---------------- MFMA GEMM: C(MxN) = A(MxK) * BT(NxK)^T ----------------
// EPI 0: C f32 plain              (G4 -> y_out)
// EPI 1: C f32 + AUX f16 col<64   (G2 -> x_dbl + dt_in)
// EPI 2: AUX f16 = softplus(acc + bias[col])   (G3 -> dt)
// EPI 3: col<2048 -> C f32 (ld 2048, xc); col>=2048 -> AUX f16 = silu(v) (z gate)
template <int EPI>
__global__ __launch_bounds__(256) void k_gemm_bt(
    const _Float16* __restrict__ A,   // M x K
    const _Float16* __restrict__ BT,  // N x K
    float* __restrict__ C,
    _Float16* __restrict__ AUX,
    const float* __restrict__ bias,
    int M, int N, int K)
{
  __shared__ __align__(16) _Float16 As[128 * 32];
  __shared__ __align__(16) _Float16 Bs[128 * 32];
  const int tid  = threadIdx.x;
  const int lane = tid & 63;
  const int wave = tid >> 6;
  const int wm = (wave >> 1) * 64;
  const int wn = (wave & 1) * 64;
  const int l15 = lane & 15;
  const int q   = lane >> 4;
  const int m0 = blockIdx.y * 128;
  const int n0 = blockIdx.x * 128;

  const int rA  = tid >> 2;   // 0..63 (4 lanes cover 64B of one row)
  const int cgA = tid & 3;

  f32x4 acc[4][4] = {};

  for (int k0 = 0; k0 < K; k0 += 32) {
    const _Float16* gA = A  + (size_t)(m0 + rA) * K + k0 + cgA * 8;
    const _Float16* gB = BT + (size_t)(n0 + rA) * K + k0 + cgA * 8;
    f16x8 a0 = *(const f16x8*)gA;
    f16x8 a1 = *(const f16x8*)(gA + (size_t)64 * K);
    f16x8 b0 = *(const f16x8*)gB;
    f16x8 b1 = *(const f16x8*)(gB + (size_t)64 * K);
    *(f16x8*)&As[(rA     ) * 32 + cgA * 8] = a0;
    *(f16x8*)&As[(rA + 64) * 32 + cgA * 8] = a1;
    *(f16x8*)&Bs[(rA     ) * 32 + cgA * 8] = b0;
    *(f16x8*)&Bs[(rA + 64) * 32 + cgA * 8] = b1;
    __syncthreads();
    f16x8 af[4], bf[4];
    #pragma unroll
    for (int i = 0; i < 4; ++i) {
      af[i] = *(const f16x8*)&As[(wm + i * 16 + l15) * 32 + q * 8];
      bf[i] = *(const f16x8*)&Bs[(wn + i * 16 + l15) * 32 + q * 8];
    }
    #pragma unroll
    for (int mi = 0; mi < 4; ++mi)
      #pragma unroll
      for (int ni = 0; ni < 4; ++ni)
        acc[mi][ni] = __builtin_amdgcn_mfma_f32_16x16x32_f16(af[mi], bf[ni], acc[mi][ni], 0, 0, 0);
    __syncthreads();
  }

  #pragma unroll
  for (int mi = 0; mi < 4; ++mi) {
    #pragma unroll
    for (int ni = 0; ni < 4; ++ni) {
      int col = n0 + wn + ni * 16 + l15;
      #pragma unroll
      for (int r = 0; r < 4; ++r) {
        int row = m0 + wm + mi * 16 + q * 4 + r;
        float v = acc[mi][ni][r];
        if constexpr (EPI == 0) {
          C[(size_t)row * N + col] = v;
        } else if constexpr (EPI == 1) {
          C[(size_t)row * N + col] = v;
          if (col < 64) AUX[(size_t)row * 64 + col] = (_Float16)v;
        } else if constexpr (EPI == 2) {
          float t = v + bias[col];
          float sp = (t > 20.f) ? t : log1pf(__expf(t));
          AUX[(size_t)row * N + col] = (_Float16)sp;
        } else {  // EPI == 3
          if (col < 2048) {
            C[(size_t)row * 2048 + col] = v;
          } else {
            AUX[(size_t)row * 2048 + (col - 2048)] = (_Float16)(v * sigmoidf_(v));
          }
        }
      }
    }
  }
}

// ---------------- causal depthwise conv (k=4) + SiLU ----------------
__global__ __launch_bounds__(256) void k_conv_silu(
    const float* __restrict__ xc, const float* __restrict__ cw,
    const float* __restrict__ cb, _Float16* __restrict__ out)
{
  int idx = blockIdx.x * 256 + threadIdx.x;  // over 4096*2048
  int d = idx & 2047;
  int row = idx >> 11;
  int t = row & 1023;
  const float* p = xc + (size_t)row * 2048 + d;
  float acc = cb[d] + cw[d * 4 + 3] * p[0];
  if (t >= 1) acc += cw[d * 4 + 2] * p[-2048];
  if (t >= 2) acc += cw[d * 4 + 1] * p[-4096];
  if (t >= 3) acc += cw[d * 4 + 0] * p[-6144];
  out[idx] = (_Float16)(acc * sigmoidf_(acc));
}

// ---------------- selective scan: one thread per (b, d), h[16] in regs ----------------
__global__ __launch_bounds__(256) void k_scan(
    const _Float16* __restrict__ dt,   // 4096 x 2048
    const float* __restrict__ xdbl,    // 4096 x 128 (cols 64..95 = B,C)
    const _Float16* __restrict__ u,    // 4096 x 2048
    const _Float16* __restrict__ zs,   // 4096 x 2048 (silu(z))
    const float* __restrict__ A_log,   // 2048 x 16
    const float* __restrict__ Dv,      // 2048
    _Float16* __restrict__ ys)         // 4096 x 2048
{
  const int tid = threadIdx.x;
  const int b = blockIdx.y;
  const int d = blockIdx.x * 256 + tid;
  float a[16];
  #pragma unroll
  for (int n = 0; n < 16; ++n) a[n] = -__expf(A_log[d * 16 + n]);
  const float Dd = Dv[d];
  float h[16];
  #pragma unroll
  for (int n = 0; n < 16; ++n) h[n] = 0.f;
  __shared__ float BC[2][32];
  const int row0 = b * 1024;
  if (tid < 32) BC[0][tid] = xdbl[(size_t)row0 * 128 + 64 + tid];
  __syncthreads();
  for (int t = 0; t < 1024; ++t) {
    const int row = row0 + t;
    const int buf = t & 1;
    if (tid < 32 && t + 1 < 1024)
      BC[buf ^ 1][tid] = xdbl[(size_t)(row + 1) * 128 + 64 + tid];
    float dtv = (float)dt[(size_t)row * 2048 + d];
    float uv  = (float)u[(size_t)row * 2048 + d];
    float zv  = (float)zs[(size_t)row * 2048 + d];
    float dtu = dtv * uv;
    float y = 0.f;
    #pragma unroll
    for (int n = 0; n < 16; ++n) {
      float dA = __expf(dtv * a[n]);
      h[n] = h[n] * dA + dtu * BC[buf][n];
      y = fmaf(h[n], BC[buf][16 + n], y);
    }
    y = fmaf(uv, Dd, y);
    ys[(size_t)row * 2048 + d] = (_Float16)(y * zv);
    __syncthreads();
  }
}

// ---------------- residual + LayerNorm + LeakyReLU ----------------
__global__ __launch_bounds__(256) void k_resid_ln(
    const float* __restrict__ x, const float* __restrict__ yo,
    const float* __restrict__ gamma, const float* __restrict__ beta,
    float* __restrict__ out)
{
  int row = blockIdx.x;
  int tid = threadIdx.x;
  float v[4];
  float s = 0.f, s2 = 0.f;
  #pragma unroll
  for (int i = 0; i < 4; ++i) {
    int c = tid + i * 256;
    float h = x[(size_t)row * 1024 + c] + yo[(size_t)row * 1024 + c];
    v[i] = h; s += h; s2 += h * h;
  }
  #pragma unroll
  for (int off = 32; off > 0; off >>= 1) {
    s  += __shfl_down(s, off, 64);
    s2 += __shfl_down(s2, off, 64);
  }
  __shared__ float rs[4], rs2[4];
  int wv = tid >> 6, ln = tid & 63;
  if (ln == 0) { rs[wv] = s; rs2[wv] = s2; }
  __syncthreads();
  if (tid == 0) {
    float a = 0.f, b2 = 0.f;
    #pragma unroll
    for (int i = 0; i < 4; ++i) { a += rs[i]; b2 += rs2[i]; }
    rs[0] = a; rs2[0] = b2;
  }
  __syncthreads();
  float mu  = rs[0] * (1.f / 1024.f);
  float var = rs2[0] * (1.f / 1024.f) - mu * mu;
  float inv = rsqrtf(var + 1e-5f);
  #pragma unroll
  for (int i = 0; i < 4; ++i) {
    int c = tid + i * 256;
    float hn = (v[i] - mu) * inv * gamma[c] + beta[c];
    out[(size_t)row * 1024 + c] = hn >= 0.f ? hn : 0.01f * hn;
  }
}

extern "C" void kernel_launch(void* const* d_in, const int* in_sizes, int n_in,
                              void* d_out, int out_size, void* d_ws, size_t ws_size,
                              hipStream_t stream)
{
  const float* x     = (const float*)d_in[0];
  const float* W_in  = (const float*)d_in[1];
  const float* convw = (const float*)d_in[2];
  const float* convb = (const float*)d_in[3];
  const float* W_x   = (const float*)d_in[4];
  const float* W_dt  = (const float*)d_in[5];
  const float* b_dt  = (const float*)d_in[6];
  const float* A_log = (const float*)d_in[7];
  const float* Dv    = (const float*)d_in[8];
  const float* W_out = (const float*)d_in[9];
  const float* gamma = (const float*)d_in[10];
  const float* beta  = (const float*)d_in[11];
  float* out = (float*)d_out;

  char* ws = (char*)d_ws;
  const size_t MB = 1ull << 20;
  _Float16* x16   = (_Float16*)(ws + 0 * MB);    // 8 MB  4096x1024
  _Float16* WinT  = (_Float16*)(ws + 8 * MB);    // 8 MB  4096x1024 (W_in^T)
  float*    xc    = (float*)   (ws + 16 * MB);   // 32 MB 4096x2048
  _Float16* zsil  = (_Float16*)(ws + 48 * MB);   // 16 MB 4096x2048 silu(z)
  _Float16* xcs   = (_Float16*)(ws + 64 * MB);   // 16 MB 4096x2048 post-conv
  _Float16* WxT   = (_Float16*)(ws + 80 * MB);   // 0.5 MB 128x2048 (padded W_x^T)
  float*    xdbl  = (float*)   (ws + 81 * MB);   // 2 MB  4096x128
  _Float16* dtin  = (_Float16*)(ws + 83 * MB);   // 0.5 MB 4096x64
  _Float16* WdtT  = (_Float16*)(ws + 84 * MB);   // 0.25 MB 2048x64 (W_dt^T)
  _Float16* dtb   = (_Float16*)(ws + 85 * MB);   // 16 MB 4096x2048 softplus(dt)
  _Float16* WoutT = (_Float16*)(ws + 101 * MB);  // 4 MB  1024x2048 (W_out^T)
  _Float16* ys    = (_Float16*)(ws + 0 * MB);    // 16 MB reuse [x16|WinT]
  float*    yout  = (float*)   (ws + 16 * MB);   // 16 MB reuse xc

  // 1. cast x to f16
  k_cast16<<<4096 * 1024 / 4 / 256, 256, 0, stream>>>(x, x16, 4096 * 1024 / 4);
  // 2. W_in^T (1024x4096 -> 4096x1024)
  k_transpose16<<<dim3(4096 / 32, 1024 / 32), dim3(32, 8), 0, stream>>>(W_in, WinT, 1024, 4096, 4096);
  // 3. G1: xz = x @ W_in ; split -> xc (f32), silu(z) (f16)
  k_gemm_bt<3><<<dim3(32, 32), 256, 0, stream>>>(x16, WinT, xc, zsil, nullptr, 4096, 4096, 1024);
  // 4. causal conv + SiLU -> xcs f16
  k_conv_silu<<<4096 * 2048 / 256, 256, 0, stream>>>(xc, convw, convb, xcs);
  // 5. W_x^T padded to 128 rows
  k_transpose16<<<dim3(128 / 32, 2048 / 32), dim3(32, 8), 0, stream>>>(W_x, WxT, 2048, 96, 128);
  // 6. G2: x_dbl = xcs @ W_x (N padded 128); also dtin f16 = cols 0..63
  k_gemm_bt<1><<<dim3(1, 32), 256, 0, stream>>>(xcs, WxT, xdbl, dtin, nullptr, 4096, 128, 2048);
  // 7. W_dt^T (64x2048 -> 2048x64)
  k_transpose16<<<dim3(2048 / 32, 64 / 32), dim3(32, 8), 0, stream>>>(W_dt, WdtT, 64, 2048, 2048);
  // 8. G3: dt = softplus(dtin @ W_dt + b_dt) -> f16
  k_gemm_bt<2><<<dim3(16, 32), 256, 0, stream>>>(dtin, WdtT, nullptr, dtb, b_dt, 4096, 2048, 64);
  // 9. selective scan + D skip + gate
  k_scan<<<dim3(8, 4), 256, 0, stream>>>(dtb, xdbl, xcs, zsil, A_log, Dv, ys);
  // 10. W_out^T (2048x1024 -> 1024x2048)
  k_transpose16<<<dim3(1024 / 32, 2048 / 32), dim3(32, 8), 0, stream>>>(W_out, WoutT, 2048, 1024, 1024);
  // 11. G4: y_out = ys @ W_out
  k_gemm_bt<0><<<dim3(8, 32), 256, 0, stream>>>(ys, WoutT, yout, nullptr, nullptr, 4096, 1024, 2048);
  // 12. residual + LN + LeakyReLU
  k_resid_ln<<<4096, 256, 0, stream>>>(x, yout, gamma, beta, out);
}

// Round 2
// 446.259 us; speedup vs baseline: 3.2561x; 3.2561x over previous
//
#include <hip/hip_runtime.h>
#include <hip/hip_fp16.h>
#include <cstdint>
#include <cstddef>

typedef _Float16 f16x8 __attribute__((ext_vector_type(8)));
typedef _Float16 f16x4 __attribute__((ext_vector_type(4)));
typedef float    f32x4 __attribute__((ext_vector_type(4)));

#define TC  32   // scan chunk length
#define NCH 32   // chunks per sequence (1024 / TC)

__device__ __forceinline__ float sigmoidf_(float x) { return 1.f / (1.f + __expf(-x)); }

// ---------------- cast f32 -> f16 (n4 = n/4 float4 groups) ----------------
__global__ __launch_bounds__(256) void k_cast16(const float* __restrict__ src,
                                                _Float16* __restrict__ dst, int n4) {
  int i = blockIdx.x * 256 + threadIdx.x;
  if (i < n4) {
    float4 v = ((const float4*)src)[i];
    f16x4 o = {(_Float16)v.x, (_Float16)v.y, (_Float16)v.z, (_Float16)v.w};
    ((f16x4*)dst)[i] = o;
  }
}

// ------- transpose + cast: src (R x C) f32 -> dst (Cpad x R) f16, zero pad -------
__global__ void k_transpose16(const float* __restrict__ src, _Float16* __restrict__ dst,
                              int R, int C, int Cpad) {
  __shared__ float tile[32][33];
  int c0 = blockIdx.x * 32, r0 = blockIdx.y * 32;
  int tx = threadIdx.x, ty = threadIdx.y;  // 32 x 8
  #pragma unroll
  for (int i = 0; i < 32; i += 8) {
    int r = r0 + ty + i, c = c0 + tx;
    tile[ty + i][tx] = (r < R && c < C) ? src[(size_t)r * C + c] : 0.f;
  }
  __syncthreads();
  #pragma unroll
  for (int i = 0; i < 32; i += 8) {
    int cc = c0 + ty + i, rr = r0 + tx;
    if (cc < Cpad && rr < R) dst[(size_t)cc * R + rr] = (_Float16)tile[tx][ty + i];
  }
}

// ---------------- MFMA GEMM: C(MxN) = A(MxK) * BT(NxK)^T ----------------
// EPI 0: C f32 plain                              (G4 -> y_out)
// EPI 1: C f32 + AUX f16 col<64                   (G2 -> x_dbl + dt_in)
// EPI 2: AUX f16 = softplus(acc + bias[col])      (G3 -> dt)
// EPI 3: col<2048 -> C16 f16 (xc); col>=2048 -> AUX f16 = silu(v) (z gate)
template <int EPI>
__global__ __launch_bounds__(256) void k_gemm_bt(
    const _Float16* __restrict__ A,   // M x K
    const _Float16* __restrict__ BT,  // N x K
    float* __restrict__ C,
    _Float16* __restrict__ C16,
    _Float16* __restrict__ AUX,
    const float* __restrict__ bias,
    int M, int N, int K)
{
  __shared__ __align__(16) _Float16 As[128 * 32];
  __shared__ __align__(16) _Float16 Bs[128 * 32];
  const int tid  = threadIdx.x;
  const int lane = tid & 63;
  const int wave = tid >> 6;
  const int wm = (wave >> 1) * 64;
  const int wn = (wave & 1) * 64;
  const int l15 = lane & 15;
  const int q   = lane >> 4;
  const int m0 = blockIdx.y * 128;
  const int n0 = blockIdx.x * 128;

  const int rA  = tid >> 2;   // 0..63
  const int cgA = tid & 3;

  f32x4 acc[4][4] = {};

  for (int k0 = 0; k0 < K; k0 += 32) {
    const _Float16* gA = A  + (size_t)(m0 + rA) * K + k0 + cgA * 8;
    const _Float16* gB = BT + (size_t)(n0 + rA) * K + k0 + cgA * 8;
    f16x8 a0 = *(const f16x8*)gA;
    f16x8 a1 = *(const f16x8*)(gA + (size_t)64 * K);
    f16x8 b0 = *(const f16x8*)gB;
    f16x8 b1 = *(const f16x8*)(gB + (size_t)64 * K);
    *(f16x8*)&As[(rA     ) * 32 + cgA * 8] = a0;
    *(f16x8*)&As[(rA + 64) * 32 + cgA * 8] = a1;
    *(f16x8*)&Bs[(rA     ) * 32 + cgA * 8] = b0;
    *(f16x8*)&Bs[(rA + 64) * 32 + cgA * 8] = b1;
    __syncthreads();
    f16x8 af[4], bf[4];
    #pragma unroll
    for (int i = 0; i < 4; ++i) {
      af[i] = *(const f16x8*)&As[(wm + i * 16 + l15) * 32 + q * 8];
      bf[i] = *(const f16x8*)&Bs[(wn + i * 16 + l15) * 32 + q * 8];
    }
    #pragma unroll
    for (int mi = 0; mi < 4; ++mi)
      #pragma unroll
      for (int ni = 0; ni < 4; ++ni)
        acc[mi][ni] = __builtin_amdgcn_mfma_f32_16x16x32_f16(af[mi], bf[ni], acc[mi][ni], 0, 0, 0);
    __syncthreads();
  }

  #pragma unroll
  for (int mi = 0; mi < 4; ++mi) {
    #pragma unroll
    for (int ni = 0; ni < 4; ++ni) {
      int col = n0 + wn + ni * 16 + l15;
      #pragma unroll
      for (int r = 0; r < 4; ++r) {
        int row = m0 + wm + mi * 16 + q * 4 + r;
        float v = acc[mi][ni][r];
        if constexpr (EPI == 0) {
          C[(size_t)row * N + col] = v;
        } else if constexpr (EPI == 1) {
          C[(size_t)row * N + col] = v;
          if (col < 64) AUX[(size_t)row * 64 + col] = (_Float16)v;
        } else if constexpr (EPI == 2) {
          float t = v + bias[col];
          float sp = (t > 20.f) ? t : log1pf(__expf(t));
          AUX[(size_t)row * N + col] = (_Float16)sp;
        } else {  // EPI == 3
          if (col < 2048) {
            C16[(size_t)row * 2048 + col] = (_Float16)v;
          } else {
            AUX[(size_t)row * 2048 + (col - 2048)] = (_Float16)(v * sigmoidf_(v));
          }
        }
      }
    }
  }
}

// ---------------- causal depthwise conv (k=4) + SiLU, f16 in/out ----------------
__global__ __launch_bounds__(256) void k_conv_silu(
    const _Float16* __restrict__ xc, const float* __restrict__ cw,
    const float* __restrict__ cb, _Float16* __restrict__ out)
{
  int idx = blockIdx.x * 256 + threadIdx.x;  // over 4096*2048
  int d = idx & 2047;
  int row = idx >> 11;
  int t = row & 1023;
  const _Float16* p = xc + (size_t)row * 2048 + d;
  float acc = cb[d] + cw[d * 4 + 3] * (float)p[0];
  if (t >= 1) acc += cw[d * 4 + 2] * (float)p[-2048];
  if (t >= 2) acc += cw[d * 4 + 1] * (float)p[-4096];
  if (t >= 3) acc += cw[d * 4 + 0] * (float)p[-6144];
  out[idx] = (_Float16)(acc * sigmoidf_(acc));
}

// ---------------- aT[n][d] = -exp(A_log[d][n]) ----------------
__global__ __launch_bounds__(256) void k_prep_a(const float* __restrict__ A_log,
                                                float* __restrict__ aT) {
  int i = blockIdx.x * 256 + threadIdx.x;  // 16*2048
  int d = i & 2047, n = i >> 11;
  aT[i] = -__expf(A_log[d * 16 + n]);
}

// ---------------- scan phase A: per-chunk local scan -> P, S ----------------
// grid (8, NCH, 4); P/S layout [b][c][n][2048]
__global__ __launch_bounds__(256) void k_scan_part(
    const _Float16* __restrict__ dt, const _Float16* __restrict__ u,
    const float* __restrict__ xdbl, const float* __restrict__ aT,
    float* __restrict__ P, float* __restrict__ S)
{
  const int tid = threadIdx.x;
  const int d = blockIdx.x * 256 + tid;
  const int c = blockIdx.y;
  const int b = blockIdx.z;
  const int row0 = b * 1024 + c * TC;
  __shared__ float Bs[TC * 16];
  for (int i = tid; i < TC * 16; i += 256) {
    int t = i >> 4, n = i & 15;
    Bs[i] = xdbl[(size_t)(row0 + t) * 128 + 64 + n];
  }
  float a[16];
  #pragma unroll
  for (int n = 0; n < 16; ++n) a[n] = aT[n * 2048 + d];
  float h[16] = {};
  float sumdt = 0.f;
  __syncthreads();
  for (int t = 0; t < TC; ++t) {
    const int row = row0 + t;
    float dtv = (float)dt[(size_t)row * 2048 + d];
    float uv  = (float)u[(size_t)row * 2048 + d];
    float dtu = dtv * uv;
    sumdt += dtv;
    #pragma unroll
    for (int n = 0; n < 16; ++n)
      h[n] = h[n] * __expf(dtv * a[n]) + dtu * Bs[t * 16 + n];
  }
  const size_t base = (size_t)(b * NCH + c) * 16 * 2048 + d;
  #pragma unroll
  for (int n = 0; n < 16; ++n) {
    P[base + n * 2048] = __expf(sumdt * a[n]);
    S[base + n * 2048] = h[n];
  }
}

// ---------------- scan phase B: combine chunk states (in-place into P) ----------------
// thread space [4][16][2048]; after: P slot c holds H_{c+1} (state entering chunk c+1)
__global__ __launch_bounds__(256) void k_scan_comb(
    float* __restrict__ P, const float* __restrict__ S)
{
  int idx = blockIdx.x * 256 + threadIdx.x;
  int d = idx & 2047;
  int n = (idx >> 11) & 15;
  int b = idx >> 15;
  float H = 0.f;
  for (int c = 0; c < NCH - 1; ++c) {
    size_t off = ((size_t)(b * NCH + c) * 16 + n) * 2048 + d;
    H = P[off] * H + S[off];
    P[off] = H;
  }
}

// ---------------- scan phase C: seeded local scan -> y, gate ----------------
__global__ __launch_bounds__(256) void k_scan_y(
    const _Float16* __restrict__ dt, const _Float16* __restrict__ u,
    const _Float16* __restrict__ zs, const float* __restrict__ xdbl,
    const float* __restrict__ aT, const float* __restrict__ Hbuf,
    const float* __restrict__ Dv, _Float16* __restrict__ ys)
{
  const int tid = threadIdx.x;
  const int d = blockIdx.x * 256 + tid;
  const int c = blockIdx.y;
  const int b = blockIdx.z;
  const int row0 = b * 1024 + c * TC;
  __shared__ float Bs[TC * 16];
  __shared__ float Cs[TC * 16];
  for (int i = tid; i < TC * 16; i += 256) {
    int t = i >> 4, n = i & 15;
    Bs[i] = xdbl[(size_t)(row0 + t) * 128 + 64 + n];
    Cs[i] = xdbl[(size_t)(row0 + t) * 128 + 80 + n];
  }
  float a[16];
  #pragma unroll
  for (int n = 0; n < 16; ++n) a[n] = aT[n * 2048 + d];
  float h[16];
  if (c == 0) {
    #pragma unroll
    for (int n = 0; n < 16; ++n) h[n] = 0.f;
  } else {
    const size_t hb = (size_t)(b * NCH + (c - 1)) * 16 * 2048 + d;
    #pragma unroll
    for (int n = 0; n < 16; ++n) h[n] = Hbuf[hb + n * 2048];
  }
  const float Dd = Dv[d];
  __syncthreads();
  for (int t = 0; t < TC; ++t) {
    const int row = row0 + t;
    float dtv = (float)dt[(size_t)row * 2048 + d];
    float uv  = (float)u[(size_t)row * 2048 + d];
    float zv  = (float)zs[(size_t)row * 2048 + d];
    float dtu = dtv * uv;
    float y = uv * Dd;
    #pragma unroll
    for (int n = 0; n < 16; ++n) {
      h[n] = h[n] * __expf(dtv * a[n]) + dtu * Bs[t * 16 + n];
      y = fmaf(h[n], Cs[t * 16 + n], y);
    }
    ys[(size_t)row * 2048 + d] = (_Float16)(y * zv);
  }
}

// ---------------- residual + LayerNorm + LeakyReLU ----------------
__global__ __launch_bounds__(256) void k_resid_ln(
    const float* __restrict__ x, const float* __restrict__ yo,
    const float* __restrict__ gamma, const float* __restrict__ beta,
    float* __restrict__ out)
{
  int row = blockIdx.x;
  int tid = threadIdx.x;
  float v[4];
  float s = 0.f, s2 = 0.f;
  #pragma unroll
  for (int i = 0; i < 4; ++i) {
    int c = tid + i * 256;
    float h = x[(size_t)row * 1024 + c] + yo[(size_t)row * 1024 + c];
    v[i] = h; s += h; s2 += h * h;
  }
  #pragma unroll
  for (int off = 32; off > 0; off >>= 1) {
    s  += __shfl_down(s, off, 64);
    s2 += __shfl_down(s2, off, 64);
  }
  __shared__ float rs[4], rs2[4];
  int wv = tid >> 6, ln = tid & 63;
  if (ln == 0) { rs[wv] = s; rs2[wv] = s2; }
  __syncthreads();
  if (tid == 0) {
    float a = 0.f, b2 = 0.f;
    #pragma unroll
    for (int i = 0; i < 4; ++i) { a += rs[i]; b2 += rs2[i]; }
    rs[0] = a; rs2[0] = b2;
  }
  __syncthreads();
  float mu  = rs[0] * (1.f / 1024.f);
  float var = rs2[0] * (1.f / 1024.f) - mu * mu;
  float inv = rsqrtf(var + 1e-5f);
  #pragma unroll
  for (int i = 0; i < 4; ++i) {
    int c = tid + i * 256;
    float hn = (v[i] - mu) * inv * gamma[c] + beta[c];
    out[(size_t)row * 1024 + c] = hn >= 0.f ? hn : 0.01f * hn;
  }
}

extern "C" void kernel_launch(void* const* d_in, const int* in_sizes, int n_in,
                              void* d_out, int out_size, void* d_ws, size_t ws_size,
                              hipStream_t stream)
{
  const float* x     = (const float*)d_in[0];
  const float* W_in  = (const float*)d_in[1];
  const float* convw = (const float*)d_in[2];
  const float* convb = (const float*)d_in[3];
  const float* W_x   = (const float*)d_in[4];
  const float* W_dt  = (const float*)d_in[5];
  const float* b_dt  = (const float*)d_in[6];
  const float* A_log = (const float*)d_in[7];
  const float* Dv    = (const float*)d_in[8];
  const float* W_out = (const float*)d_in[9];
  const float* gamma = (const float*)d_in[10];
  const float* beta  = (const float*)d_in[11];
  float* out = (float*)d_out;

  char* ws = (char*)d_ws;
  const size_t MB = 1ull << 20;
  // lifetimes: x16/WinT die after G1; xc16 dies after conv; P/S die after scan C
  _Float16* x16   = (_Float16*)(ws + 0 * MB);            // 8 MB   4096x1024
  _Float16* WinT  = (_Float16*)(ws + 8 * MB);            // 8 MB   4096x1024
  _Float16* xc16  = (_Float16*)(ws + 16 * MB);           // 16 MB  4096x2048 pre-conv
  _Float16* zsil  = (_Float16*)(ws + 32 * MB);           // 16 MB  silu(z)
  _Float16* xcs   = (_Float16*)(ws + 48 * MB);           // 16 MB  post-conv u
  _Float16* dtb   = (_Float16*)(ws + 64 * MB);           // 16 MB  softplus(dt)
  _Float16* WxT   = (_Float16*)(ws + 80 * MB);           // 0.5 MB 128x2048
  float*    xdbl  = (float*)   (ws + 80 * MB + 512 * 1024);   // 2 MB 4096x128
  _Float16* dtin  = (_Float16*)(ws + 82 * MB + 512 * 1024);   // 0.5 MB 4096x64
  _Float16* WdtT  = (_Float16*)(ws + 83 * MB);           // 0.25 MB 2048x64
  float*    aT    = (float*)   (ws + 83 * MB + 256 * 1024);   // 0.125 MB 16x2048
  _Float16* WoutT = (_Float16*)(ws + 84 * MB);           // 4 MB   1024x2048
  _Float16* ysb   = (_Float16*)(ws + 88 * MB);           // 16 MB  gated y
  float*    Pb    = (float*)   (ws + 16 * MB);           // 16 MB  reuse xc16
  float*    Sb    = (float*)   (ws + 0 * MB);            // 16 MB  reuse x16+WinT
  float*    yout  = (float*)   (ws + 0 * MB);            // 16 MB  reuse Sb after scan

  // 1. cast x to f16
  k_cast16<<<4096 * 1024 / 4 / 256, 256, 0, stream>>>(x, x16, 4096 * 1024 / 4);
  // 2. W_in^T (1024x4096 -> 4096x1024)
  k_transpose16<<<dim3(4096 / 32, 1024 / 32), dim3(32, 8), 0, stream>>>(W_in, WinT, 1024, 4096, 4096);
  // 3. G1: xz = x @ W_in ; xc f16 + silu(z) f16
  k_gemm_bt<3><<<dim3(32, 32), 256, 0, stream>>>(x16, WinT, nullptr, xc16, zsil, nullptr, 4096, 4096, 1024);
  // 4. causal conv + SiLU
  k_conv_silu<<<4096 * 2048 / 256, 256, 0, stream>>>(xc16, convw, convb, xcs);
  // 5. W_x^T padded to 128 rows
  k_transpose16<<<dim3(128 / 32, 2048 / 32), dim3(32, 8), 0, stream>>>(W_x, WxT, 2048, 96, 128);
  // 6. G2: x_dbl = xcs @ W_x ; dtin f16 = cols 0..63
  k_gemm_bt<1><<<dim3(1, 32), 256, 0, stream>>>(xcs, WxT, xdbl, nullptr, dtin, nullptr, 4096, 128, 2048);
  // 7. W_dt^T
  k_transpose16<<<dim3(2048 / 32, 64 / 32), dim3(32, 8), 0, stream>>>(W_dt, WdtT, 64, 2048, 2048);
  // 8. G3: dt = softplus(dtin @ W_dt + b_dt)
  k_gemm_bt<2><<<dim3(16, 32), 256, 0, stream>>>(dtin, WdtT, nullptr, nullptr, dtb, b_dt, 4096, 2048, 64);
  // 9. chunked selective scan
  k_prep_a<<<16 * 2048 / 256, 256, 0, stream>>>(A_log, aT);
  k_scan_part<<<dim3(8, NCH, 4), 256, 0, stream>>>(dtb, xcs, xdbl, aT, Pb, Sb);
  k_scan_comb<<<4 * 16 * 2048 / 256, 256, 0, stream>>>(Pb, Sb);
  k_scan_y<<<dim3(8, NCH, 4), 256, 0, stream>>>(dtb, xcs, zsil, xdbl, aT, Pb, Dv, ysb);
  // 10. W_out^T
  k_transpose16<<<dim3(1024 / 32, 2048 / 32), dim3(32, 8), 0, stream>>>(W_out, WoutT, 2048, 1024, 1024);
  // 11. G4: y_out = ys @ W_out
  k_gemm_bt<0><<<dim3(8, 32), 256, 0, stream>>>(ysb, WoutT, yout, nullptr, nullptr, nullptr, 4096, 1024, 2048);
  // 12. residual + LN + LeakyReLU
  k_resid_ln<<<4096, 256, 0, stream>>>(x, yout, gamma, beta, out);
}

// Round 3
// 410.152 us; speedup vs baseline: 3.5427x; 1.0880x over previous
//
#include <hip/hip_runtime.h>
#include <hip/hip_fp16.h>
#include <cstdint>
#include <cstddef>

typedef _Float16 f16x8 __attribute__((ext_vector_type(8)));
typedef _Float16 f16x4 __attribute__((ext_vector_type(4)));
typedef float    f32x4 __attribute__((ext_vector_type(4)));

#define TC  32   // scan chunk length
#define NCH 32   // chunks per sequence (1024 / TC)

__device__ __forceinline__ float sigmoidf_(float x) { return 1.f / (1.f + __expf(-x)); }

// async global -> LDS, 16 bytes per lane (lands at wave-uniform base + lane*16)
__device__ __forceinline__ void gload_lds16(const _Float16* g, _Float16* l) {
  __builtin_amdgcn_global_load_lds(
      (const __attribute__((address_space(1))) void*)g,
      (__attribute__((address_space(3))) void*)l, 16, 0, 0);
}

// ---------------- cast f32 -> f16 ----------------
__global__ __launch_bounds__(256) void k_cast16(const float* __restrict__ src,
                                                _Float16* __restrict__ dst, int n4) {
  int i = blockIdx.x * 256 + threadIdx.x;
  if (i < n4) {
    float4 v = ((const float4*)src)[i];
    f16x4 o = {(_Float16)v.x, (_Float16)v.y, (_Float16)v.z, (_Float16)v.w};
    ((f16x4*)dst)[i] = o;
  }
}

// ------- transpose + cast: src (R x C) f32 -> dst (Cpad x R) f16, zero pad -------
__global__ void k_transpose16(const float* __restrict__ src, _Float16* __restrict__ dst,
                              int R, int C, int Cpad) {
  __shared__ float tile[32][33];
  int c0 = blockIdx.x * 32, r0 = blockIdx.y * 32;
  int tx = threadIdx.x, ty = threadIdx.y;  // 32 x 8
  #pragma unroll
  for (int i = 0; i < 32; i += 8) {
    int r = r0 + ty + i, c = c0 + tx;
    tile[ty + i][tx] = (r < R && c < C) ? src[(size_t)r * C + c] : 0.f;
  }
  __syncthreads();
  #pragma unroll
  for (int i = 0; i < 32; i += 8) {
    int cc = c0 + ty + i, rr = r0 + tx;
    if (cc < Cpad && rr < R) dst[(size_t)cc * R + rr] = (_Float16)tile[tx][ty + i];
  }
}

// ---------------- MFMA GEMM: C(MxN) = A(MxK) * BT(NxK)^T ----------------
// m97-style: global_load_lds(16B) staging + XOR bank swizzle.
// EPI 0: C f32 plain                              (G4 -> y_out)
// EPI 2: AUX f16 = softplus(acc + bias[col])      (G3 -> dt)
// EPI 3: col<2048 -> C16 f16 (xc); col>=2048 -> AUX f16 = silu(v) (z)
// EPI 4: partial f32 to C + z*M*N (split-K over blockIdx.z, 512 each) (G2)
template <int EPI>
__global__ __launch_bounds__(256) void k_gemm_bt(
    const _Float16* __restrict__ A,   // M x K
    const _Float16* __restrict__ BT,  // N x K
    float* __restrict__ C,
    _Float16* __restrict__ C16,
    _Float16* __restrict__ AUX,
    const float* __restrict__ bias,
    int M, int N, int K)
{
  __shared__ __align__(16) _Float16 As[128 * 32];
  __shared__ __align__(16) _Float16 Bs[128 * 32];
  const int tid  = threadIdx.x;
  const int lane = tid & 63;
  const int wave = tid >> 6;
  const int wm = (wave >> 1) * 64;
  const int wn = (wave & 1) * 64;
  const int l15 = lane & 15;
  const int q   = lane >> 4;
  const int m0 = blockIdx.y * 128;
  const int n0 = blockIdx.x * 128;

  int k0 = 0, kend = K;
  if constexpr (EPI == 4) { k0 = blockIdx.z * 512; kend = k0 + 512; }

  // staging: wave w owns 16-row chunks {2w, 2w+1} of both tiles.
  // lane -> row (lane>>2), LDS pos p = lane&3; global colgroup g = p ^ ((row>>1)&3)
  const int rowA0 = wave * 32 + (lane >> 2);
  const int g     = (lane & 3) ^ ((lane >> 3) & 3);
  const _Float16* gA0 = A  + (size_t)(m0 + rowA0) * K + g * 8 + k0;
  const _Float16* gA1 = gA0 + (size_t)16 * K;
  const _Float16* gB0 = BT + (size_t)(n0 + rowA0) * K + g * 8 + k0;
  const _Float16* gB1 = gB0 + (size_t)16 * K;
  _Float16* lA0 = As + wave * 1024 + lane * 8;   // chunk = 512 f16 = 1024 B
  _Float16* lA1 = lA0 + 512;
  _Float16* lB0 = Bs + wave * 1024 + lane * 8;
  _Float16* lB1 = lB0 + 512;

  const int posq = q ^ ((l15 >> 1) & 3);  // swizzled 16B slot for fragment reads

  f32x4 acc[4][4] = {};

  for (int k = 0; k < kend - k0; k += 32) {
    gload_lds16(gA0 + k, lA0);
    gload_lds16(gA1 + k, lA1);
    gload_lds16(gB0 + k, lB0);
    gload_lds16(gB1 + k, lB1);
    __syncthreads();
    f16x8 af[4], bf[4];
    #pragma unroll
    for (int i = 0; i < 4; ++i) {
      af[i] = *(const f16x8*)&As[(wm + i * 16 + l15) * 32 + posq * 8];
      bf[i] = *(const f16x8*)&Bs[(wn + i * 16 + l15) * 32 + posq * 8];
    }
    #pragma unroll
    for (int mi = 0; mi < 4; ++mi)
      #pragma unroll
      for (int ni = 0; ni < 4; ++ni)
        acc[mi][ni] = __builtin_amdgcn_mfma_f32_16x16x32_f16(af[mi], bf[ni], acc[mi][ni], 0, 0, 0);
    __syncthreads();
  }

  #pragma unroll
  for (int mi = 0; mi < 4; ++mi) {
    #pragma unroll
    for (int ni = 0; ni < 4; ++ni) {
      int col = n0 + wn + ni * 16 + l15;
      #pragma unroll
      for (int r = 0; r < 4; ++r) {
        int row = m0 + wm + mi * 16 + q * 4 + r;
        float v = acc[mi][ni][r];
        if constexpr (EPI == 0) {
          C[(size_t)row * N + col] = v;
        } else if constexpr (EPI == 2) {
          float t = v + bias[col];
          float sp = (t > 20.f) ? t : log1pf(__expf(t));
          AUX[(size_t)row * N + col] = (_Float16)sp;
        } else if constexpr (EPI == 3) {
          if (col < 2048) {
            C16[(size_t)row * 2048 + col] = (_Float16)v;
          } else {
            AUX[(size_t)row * 2048 + (col - 2048)] = (_Float16)(v * sigmoidf_(v));
          }
        } else {  // EPI == 4: split-K partial
          C[(size_t)blockIdx.z * M * N + (size_t)row * N + col] = v;
        }
      }
    }
  }
}

// ---------------- reduce split-K partials -> xdbl f32 (+ dtin f16 cols<64) ----------------
__global__ __launch_bounds__(256) void k_red4(const float* __restrict__ Cp,
                                              float* __restrict__ xdbl,
                                              _Float16* __restrict__ dtin) {
  int i = blockIdx.x * 256 + threadIdx.x;  // 4096*128
  const int PL = 4096 * 128;
  float s = Cp[i] + Cp[i + PL] + Cp[i + 2 * PL] + Cp[i + 3 * PL];
  xdbl[i] = s;
  int col = i & 127;
  if (col < 64) dtin[(size_t)(i >> 7) * 64 + col] = (_Float16)s;
}

// ---------------- causal depthwise conv (k=4) + SiLU, f16 in/out ----------------
__global__ __launch_bounds__(256) void k_conv_silu(
    const _Float16* __restrict__ xc, const float* __restrict__ cw,
    const float* __restrict__ cb, _Float16* __restrict__ out)
{
  int idx = blockIdx.x * 256 + threadIdx.x;  // over 4096*2048
  int d = idx & 2047;
  int row = idx >> 11;
  int t = row & 1023;
  const _Float16* p = xc + (size_t)row * 2048 + d;
  float acc = cb[d] + cw[d * 4 + 3] * (float)p[0];
  if (t >= 1) acc += cw[d * 4 + 2] * (float)p[-2048];
  if (t >= 2) acc += cw[d * 4 + 1] * (float)p[-4096];
  if (t >= 3) acc += cw[d * 4 + 0] * (float)p[-6144];
  out[idx] = (_Float16)(acc * sigmoidf_(acc));
}

// ---------------- aT[n][d] = -exp(A_log[d][n]) ----------------
__global__ __launch_bounds__(256) void k_prep_a(const float* __restrict__ A_log,
                                                float* __restrict__ aT) {
  int i = blockIdx.x * 256 + threadIdx.x;  // 16*2048
  int d = i & 2047, n = i >> 11;
  aT[i] = -__expf(A_log[d * 16 + n]);
}

// ---------------- scan phase A: per-chunk local scan -> P, S ----------------
__global__ __launch_bounds__(256) void k_scan_part(
    const _Float16* __restrict__ dt, const _Float16* __restrict__ u,
    const float* __restrict__ xdbl, const float* __restrict__ aT,
    float* __restrict__ P, float* __restrict__ S)
{
  const int tid = threadIdx.x;
  const int d = blockIdx.x * 256 + tid;
  const int c = blockIdx.y;
  const int b = blockIdx.z;
  const int row0 = b * 1024 + c * TC;
  __shared__ float Bs[TC * 16];
  for (int i = tid; i < TC * 16; i += 256) {
    int t = i >> 4, n = i & 15;
    Bs[i] = xdbl[(size_t)(row0 + t) * 128 + 64 + n];
  }
  float a[16];
  #pragma unroll
  for (int n = 0; n < 16; ++n) a[n] = aT[n * 2048 + d];
  float h[16] = {};
  float sumdt = 0.f;
  __syncthreads();
  for (int t = 0; t < TC; ++t) {
    const int row = row0 + t;
    float dtv = (float)dt[(size_t)row * 2048 + d];
    float uv  = (float)u[(size_t)row * 2048 + d];
    float dtu = dtv * uv;
    sumdt += dtv;
    #pragma unroll
    for (int n = 0; n < 16; ++n)
      h[n] = h[n] * __expf(dtv * a[n]) + dtu * Bs[t * 16 + n];
  }
  const size_t base = (size_t)(b * NCH + c) * 16 * 2048 + d;
  #pragma unroll
  for (int n = 0; n < 16; ++n) {
    P[base + n * 2048] = __expf(sumdt * a[n]);
    S[base + n * 2048] = h[n];
  }
}

// ---------------- scan phase B: combine chunk states (in-place into P) ----------------
__global__ __launch_bounds__(256) void k_scan_comb(
    float* __restrict__ P, const float* __restrict__ S)
{
  int idx = blockIdx.x * 256 + threadIdx.x;
  int d = idx & 2047;
  int n = (idx >> 11) & 15;
  int b = idx >> 15;
  float H = 0.f;
  for (int c = 0; c < NCH - 1; ++c) {
    size_t off = ((size_t)(b * NCH + c) * 16 + n) * 2048 + d;
    H = P[off] * H + S[off];
    P[off] = H;
  }
}

// ---------------- scan phase C: seeded local scan -> y, gate ----------------
__global__ __launch_bounds__(256) void k_scan_y(
    const _Float16* __restrict__ dt, const _Float16* __restrict__ u,
    const _Float16* __restrict__ zs, const float* __restrict__ xdbl,
    const float* __restrict__ aT, const float* __restrict__ Hbuf,
    const float* __restrict__ Dv, _Float16* __restrict__ ys)
{
  const int tid = threadIdx.x;
  const int d = blockIdx.x * 256 + tid;
  const int c = blockIdx.y;
  const int b = blockIdx.z;
  const int row0 = b * 1024 + c * TC;
  __shared__ float Bs[TC * 16];
  __shared__ float Cs[TC * 16];
  for (int i = tid; i < TC * 16; i += 256) {
    int t = i >> 4, n = i & 15;
    Bs[i] = xdbl[(size_t)(row0 + t) * 128 + 64 + n];
    Cs[i] = xdbl[(size_t)(row0 + t) * 128 + 80 + n];
  }
  float a[16];
  #pragma unroll
  for (int n = 0; n < 16; ++n) a[n] = aT[n * 2048 + d];
  float h[16];
  if (c == 0) {
    #pragma unroll
    for (int n = 0; n < 16; ++n) h[n] = 0.f;
  } else {
    const size_t hb = (size_t)(b * NCH + (c - 1)) * 16 * 2048 + d;
    #pragma unroll
    for (int n = 0; n < 16; ++n) h[n] = Hbuf[hb + n * 2048];
  }
  const float Dd = Dv[d];
  __syncthreads();
  for (int t = 0; t < TC; ++t) {
    const int row = row0 + t;
    float dtv = (float)dt[(size_t)row * 2048 + d];
    float uv  = (float)u[(size_t)row * 2048 + d];
    float zv  = (float)zs[(size_t)row * 2048 + d];
    float dtu = dtv * uv;
    float y = uv * Dd;
    #pragma unroll
    for (int n = 0; n < 16; ++n) {
      h[n] = h[n] * __expf(dtv * a[n]) + dtu * Bs[t * 16 + n];
      y = fmaf(h[n], Cs[t * 16 + n], y);
    }
    ys[(size_t)row * 2048 + d] = (_Float16)(y * zv);
  }
}

// ---------------- residual + LayerNorm + LeakyReLU ----------------
__global__ __launch_bounds__(256) void k_resid_ln(
    const float* __restrict__ x, const float* __restrict__ yo,
    const float* __restrict__ gamma, const float* __restrict__ beta,
    float* __restrict__ out)
{
  int row = blockIdx.x;
  int tid = threadIdx.x;
  float v[4];
  float s = 0.f, s2 = 0.f;
  #pragma unroll
  for (int i = 0; i < 4; ++i) {
    int c = tid + i * 256;
    float h = x[(size_t)row * 1024 + c] + yo[(size_t)row * 1024 + c];
    v[i] = h; s += h; s2 += h * h;
  }
  #pragma unroll
  for (int off = 32; off > 0; off >>= 1) {
    s  += __shfl_down(s, off, 64);
    s2 += __shfl_down(s2, off, 64);
  }
  __shared__ float rs[4], rs2[4];
  int wv = tid >> 6, ln = tid & 63;
  if (ln == 0) { rs[wv] = s; rs2[wv] = s2; }
  __syncthreads();
  if (tid == 0) {
    float a = 0.f, b2 = 0.f;
    #pragma unroll
    for (int i = 0; i < 4; ++i) { a += rs[i]; b2 += rs2[i]; }
    rs[0] = a; rs2[0] = b2;
  }
  __syncthreads();
  float mu  = rs[0] * (1.f / 1024.f);
  float var = rs2[0] * (1.f / 1024.f) - mu * mu;
  float inv = rsqrtf(var + 1e-5f);
  #pragma unroll
  for (int i = 0; i < 4; ++i) {
    int c = tid + i * 256;
    float hn = (v[i] - mu) * inv * gamma[c] + beta[c];
    out[(size_t)row * 1024 + c] = hn >= 0.f ? hn : 0.01f * hn;
  }
}

extern "C" void kernel_launch(void* const* d_in, const int* in_sizes, int n_in,
                              void* d_out, int out_size, void* d_ws, size_t ws_size,
                              hipStream_t stream)
{
  const float* x     = (const float*)d_in[0];
  const float* W_in  = (const float*)d_in[1];
  const float* convw = (const float*)d_in[2];
  const float* convb = (const float*)d_in[3];
  const float* W_x   = (const float*)d_in[4];
  const float* W_dt  = (const float*)d_in[5];
  const float* b_dt  = (const float*)d_in[6];
  const float* A_log = (const float*)d_in[7];
  const float* Dv    = (const float*)d_in[8];
  const float* W_out = (const float*)d_in[9];
  const float* gamma = (const float*)d_in[10];
  const float* beta  = (const float*)d_in[11];
  float* out = (float*)d_out;

  char* ws = (char*)d_ws;
  const size_t MB = 1ull << 20;
  _Float16* x16   = (_Float16*)(ws + 0 * MB);            // 8 MB   4096x1024
  _Float16* WinT  = (_Float16*)(ws + 8 * MB);            // 8 MB   4096x1024
  _Float16* xc16  = (_Float16*)(ws + 16 * MB);           // 16 MB  pre-conv xc
  _Float16* zsil  = (_Float16*)(ws + 32 * MB);           // 16 MB  silu(z)
  _Float16* xcs   = (_Float16*)(ws + 48 * MB);           // 16 MB  post-conv u
  _Float16* dtb   = (_Float16*)(ws + 64 * MB);           // 16 MB  softplus(dt)
  _Float16* WxT   = (_Float16*)(ws + 80 * MB);           // 0.5 MB 128x2048
  float*    xdbl  = (float*)   (ws + 80 * MB + 512 * 1024);   // 2 MB 4096x128
  _Float16* dtin  = (_Float16*)(ws + 82 * MB + 512 * 1024);   // 0.5 MB 4096x64
  _Float16* WdtT  = (_Float16*)(ws + 83 * MB);           // 0.25 MB 2048x64
  float*    aT    = (float*)   (ws + 83 * MB + 256 * 1024);   // 0.125 MB 16x2048
  _Float16* WoutT = (_Float16*)(ws + 84 * MB);           // 4 MB   1024x2048
  _Float16* ysb   = (_Float16*)(ws + 88 * MB);           // 16 MB  gated y
  float*    Cpart = (float*)   (ws + 16 * MB);           // 8 MB   reuse xc16 (dead after conv, before scan)
  float*    Pb    = (float*)   (ws + 16 * MB);           // 16 MB  reuse xc16
  float*    Sb    = (float*)   (ws + 0 * MB);            // 16 MB  reuse x16+WinT
  float*    yout  = (float*)   (ws + 0 * MB);            // 16 MB  reuse Sb after scan

  // 1. cast x to f16
  k_cast16<<<4096 * 1024 / 4 / 256, 256, 0, stream>>>(x, x16, 4096 * 1024 / 4);
  // 2. W_in^T (1024x4096 -> 4096x1024)
  k_transpose16<<<dim3(4096 / 32, 1024 / 32), dim3(32, 8), 0, stream>>>(W_in, WinT, 1024, 4096, 4096);
  // 3. G1: xz = x @ W_in ; xc f16 + silu(z) f16
  k_gemm_bt<3><<<dim3(32, 32), 256, 0, stream>>>(x16, WinT, nullptr, xc16, zsil, nullptr, 4096, 4096, 1024);
  // 4. causal conv + SiLU
  k_conv_silu<<<4096 * 2048 / 256, 256, 0, stream>>>(xc16, convw, convb, xcs);
  // 5. W_x^T padded to 128 rows
  k_transpose16<<<dim3(128 / 32, 2048 / 32), dim3(32, 8), 0, stream>>>(W_x, WxT, 2048, 96, 128);
  // 6. G2 split-K: partials then reduce -> xdbl f32, dtin f16
  k_gemm_bt<4><<<dim3(1, 32, 4), 256, 0, stream>>>(xcs, WxT, Cpart, nullptr, nullptr, nullptr, 4096, 128, 2048);
  k_red4<<<4096 * 128 / 256, 256, 0, stream>>>(Cpart, xdbl, dtin);
  // 7. W_dt^T
  k_transpose16<<<dim3(2048 / 32, 64 / 32), dim3(32, 8), 0, stream>>>(W_dt, WdtT, 64, 2048, 2048);
  // 8. G3: dt = softplus(dtin @ W_dt + b_dt)
  k_gemm_bt<2><<<dim3(16, 32), 256, 0, stream>>>(dtin, WdtT, nullptr, nullptr, dtb, b_dt, 4096, 2048, 64);
  // 9. chunked selective scan
  k_prep_a<<<16 * 2048 / 256, 256, 0, stream>>>(A_log, aT);
  k_scan_part<<<dim3(8, NCH, 4), 256, 0, stream>>>(dtb, xcs, xdbl, aT, Pb, Sb);
  k_scan_comb<<<4 * 16 * 2048 / 256, 256, 0, stream>>>(Pb, Sb);
  k_scan_y<<<dim3(8, NCH, 4), 256, 0, stream>>>(dtb, xcs, zsil, xdbl, aT, Pb, Dv, ysb);
  // 10. W_out^T
  k_transpose16<<<dim3(1024 / 32, 2048 / 32), dim3(32, 8), 0, stream>>>(W_out, WoutT, 2048, 1024, 1024);
  // 11. G4: y_out = ys @ W_out
  k_gemm_bt<0><<<dim3(8, 32), 256, 0, stream>>>(ysb, WoutT, yout, nullptr, nullptr, nullptr, 4096, 1024, 2048);
  // 12. residual + LN + LeakyReLU
  k_resid_ln<<<4096, 256, 0, stream>>>(x, yout, gamma, beta, out);
}

// Round 4
// 386.494 us; speedup vs baseline: 3.7596x; 1.0612x over previous
//
#include <hip/hip_runtime.h>
#include <hip/hip_fp16.h>
#include <cstdint>
#include <cstddef>

typedef _Float16 f16x8 __attribute__((ext_vector_type(8)));
typedef _Float16 f16x4 __attribute__((ext_vector_type(4)));
typedef float    f32x4 __attribute__((ext_vector_type(4)));

#define TC  32   // scan chunk length
#define NCH 32   // chunks per sequence (1024 / TC)

__device__ __forceinline__ float sigmoidf_(float x) { return 1.f / (1.f + __expf(-x)); }

// async global -> LDS, 16 bytes per lane (wave-uniform base + lane*16)
__device__ __forceinline__ void gload_lds16(const _Float16* g, _Float16* l) {
  __builtin_amdgcn_global_load_lds(
      (const __attribute__((address_space(1))) void*)g,
      (__attribute__((address_space(3))) void*)l, 16, 0, 0);
}

// ---------------- cast f32 -> f16 ----------------
__global__ __launch_bounds__(256) void k_cast16(const float* __restrict__ src,
                                                _Float16* __restrict__ dst, int n4) {
  int i = blockIdx.x * 256 + threadIdx.x;
  if (i < n4) {
    float4 v = ((const float4*)src)[i];
    f16x4 o = {(_Float16)v.x, (_Float16)v.y, (_Float16)v.z, (_Float16)v.w};
    ((f16x4*)dst)[i] = o;
  }
}

// ------- transpose + cast: src (R x C) f32 -> dst (Cpad x R) f16, zero pad -------
__global__ void k_transpose16(const float* __restrict__ src, _Float16* __restrict__ dst,
                              int R, int C, int Cpad) {
  __shared__ float tile[32][33];
  int c0 = blockIdx.x * 32, r0 = blockIdx.y * 32;
  int tx = threadIdx.x, ty = threadIdx.y;  // 32 x 8
  #pragma unroll
  for (int i = 0; i < 32; i += 8) {
    int r = r0 + ty + i, c = c0 + tx;
    tile[ty + i][tx] = (r < R && c < C) ? src[(size_t)r * C + c] : 0.f;
  }
  __syncthreads();
  #pragma unroll
  for (int i = 0; i < 32; i += 8) {
    int cc = c0 + ty + i, rr = r0 + tx;
    if (cc < Cpad && rr < R) dst[(size_t)cc * R + rr] = (_Float16)tile[tx][ty + i];
  }
}

// ---------------- MFMA GEMM, BK=64: C(MxN) = A(MxK) * BT(NxK)^T ----------------
// Split-K over blockIdx.z (kpb = K/gridDim.z), partials at C + z*M*N.
// EPI 2: AUX f16 = softplus(acc + bias[col])      (G3 -> dt)
// EPI 3: col<2048 -> C16 f16 (xc); col>=2048 -> AUX f16 = silu(v) (z)   (G1)
// EPI 4: C f32 partial (G2 z=4, G4 z=2)
template <int EPI>
__global__ __launch_bounds__(256) void k_gemm_bt(
    const _Float16* __restrict__ A,   // M x K
    const _Float16* __restrict__ BT,  // N x K
    float* __restrict__ C,
    _Float16* __restrict__ C16,
    _Float16* __restrict__ AUX,
    const float* __restrict__ bias,
    int M, int N, int K)
{
  // 128 rows x 64 cols f16 per tile; row = 128 B (full bank wrap), 8 slots of 16 B.
  // slot swizzle: logical s at row r stored at phys p = s ^ (r & 7)
  __shared__ __align__(16) _Float16 As[128 * 64];
  __shared__ __align__(16) _Float16 Bs[128 * 64];
  const int tid  = threadIdx.x;
  const int lane = tid & 63;
  const int wave = tid >> 6;
  const int wm = (wave >> 1) * 64;
  const int wn = (wave & 1) * 64;
  const int l15 = lane & 15;
  const int q   = lane >> 4;
  const int m0 = blockIdx.y * 128;
  const int n0 = blockIdx.x * 128;

  const int kpb = K / gridDim.z;
  const int k0  = blockIdx.z * kpb;

  // staging: wave owns rows [wave*32, wave*32+32) of A and B; 4 chunks x 8 rows each.
  // lane -> row (lane>>3) within chunk, phys slot lane&7; global colgroup g = (lane&7)^((lane>>3)&7)
  const int rch = lane >> 3;
  const int g   = (lane & 7) ^ (rch & 7);
  const _Float16* gA = A  + (size_t)(m0 + wave * 32 + rch) * K + k0 + g * 8;
  const _Float16* gB = BT + (size_t)(n0 + wave * 32 + rch) * K + k0 + g * 8;
  _Float16* lA = As + wave * 32 * 64 + lane * 8;
  _Float16* lB = Bs + wave * 32 * 64 + lane * 8;

  const int sx = l15 & 7;  // read-side swizzle term

  f32x4 acc[4][4] = {};

  for (int k = 0; k < kpb; k += 64) {
    #pragma unroll
    for (int c = 0; c < 4; ++c) {
      gload_lds16(gA + (size_t)(c * 8) * K + k, lA + c * 512);
      gload_lds16(gB + (size_t)(c * 8) * K + k, lB + c * 512);
    }
    __syncthreads();
    #pragma unroll
    for (int k32 = 0; k32 < 2; ++k32) {
      f16x8 af[4], bf[4];
      #pragma unroll
      for (int i = 0; i < 4; ++i) {
        af[i] = *(const f16x8*)&As[(wm + i * 16 + l15) * 64 + ((k32 * 4 + q) ^ sx) * 8];
        bf[i] = *(const f16x8*)&Bs[(wn + i * 16 + l15) * 64 + ((k32 * 4 + q) ^ sx) * 8];
      }
      #pragma unroll
      for (int mi = 0; mi < 4; ++mi)
        #pragma unroll
        for (int ni = 0; ni < 4; ++ni)
          acc[mi][ni] = __builtin_amdgcn_mfma_f32_16x16x32_f16(af[mi], bf[ni], acc[mi][ni], 0, 0, 0);
    }
    __syncthreads();
  }

  #pragma unroll
  for (int mi = 0; mi < 4; ++mi) {
    #pragma unroll
    for (int ni = 0; ni < 4; ++ni) {
      int col = n0 + wn + ni * 16 + l15;
      #pragma unroll
      for (int r = 0; r < 4; ++r) {
        int row = m0 + wm + mi * 16 + q * 4 + r;
        float v = acc[mi][ni][r];
        if constexpr (EPI == 2) {
          float t = v + bias[col];
          float sp = (t > 20.f) ? t : log1pf(__expf(t));
          AUX[(size_t)row * N + col] = (_Float16)sp;
        } else if constexpr (EPI == 3) {
          if (col < 2048) {
            C16[(size_t)row * 2048 + col] = (_Float16)v;
          } else {
            AUX[(size_t)row * 2048 + (col - 2048)] = (_Float16)(v * sigmoidf_(v));
          }
        } else {  // EPI == 4: split-K partial
          C[(size_t)blockIdx.z * M * N + (size_t)row * N + col] = v;
        }
      }
    }
  }
}

// ---------------- reduce G2 split-K partials -> xdbl f32 (+ dtin f16 cols<64) ----------------
__global__ __launch_bounds__(256) void k_red4(const float* __restrict__ Cp,
                                              float* __restrict__ xdbl,
                                              _Float16* __restrict__ dtin) {
  int i = blockIdx.x * 256 + threadIdx.x;  // 4096*128
  const int PL = 4096 * 128;
  float s = Cp[i] + Cp[i + PL] + Cp[i + 2 * PL] + Cp[i + 3 * PL];
  xdbl[i] = s;
  int col = i & 127;
  if (col < 64) dtin[(size_t)(i >> 7) * 64 + col] = (_Float16)s;
}

// ---------------- causal depthwise conv (k=4) + SiLU, f16 in/out ----------------
__global__ __launch_bounds__(256) void k_conv_silu(
    const _Float16* __restrict__ xc, const float* __restrict__ cw,
    const float* __restrict__ cb, _Float16* __restrict__ out)
{
  int idx = blockIdx.x * 256 + threadIdx.x;  // over 4096*2048
  int d = idx & 2047;
  int row = idx >> 11;
  int t = row & 1023;
  const _Float16* p = xc + (size_t)row * 2048 + d;
  float acc = cb[d] + cw[d * 4 + 3] * (float)p[0];
  if (t >= 1) acc += cw[d * 4 + 2] * (float)p[-2048];
  if (t >= 2) acc += cw[d * 4 + 1] * (float)p[-4096];
  if (t >= 3) acc += cw[d * 4 + 0] * (float)p[-6144];
  out[idx] = (_Float16)(acc * sigmoidf_(acc));
}

// ---------------- scan phase A: per-chunk local scan -> P, S ----------------
__global__ __launch_bounds__(256) void k_scan_part(
    const _Float16* __restrict__ dt, const _Float16* __restrict__ u,
    const float* __restrict__ xdbl, const float* __restrict__ A_log,
    float* __restrict__ P, float* __restrict__ S)
{
  const int tid = threadIdx.x;
  const int d = blockIdx.x * 256 + tid;
  const int c = blockIdx.y;
  const int b = blockIdx.z;
  const int row0 = b * 1024 + c * TC;
  __shared__ float Bs[TC * 16];
  for (int i = tid; i < TC * 16; i += 256) {
    int t = i >> 4, n = i & 15;
    Bs[i] = xdbl[(size_t)(row0 + t) * 128 + 64 + n];
  }
  float a[16];
  #pragma unroll
  for (int n = 0; n < 16; ++n) a[n] = -__expf(A_log[d * 16 + n]);
  float h[16] = {};
  float sumdt = 0.f;
  __syncthreads();
  for (int t = 0; t < TC; ++t) {
    const int row = row0 + t;
    float dtv = (float)dt[(size_t)row * 2048 + d];
    float uv  = (float)u[(size_t)row * 2048 + d];
    float dtu = dtv * uv;
    sumdt += dtv;
    #pragma unroll
    for (int n = 0; n < 16; ++n)
      h[n] = h[n] * __expf(dtv * a[n]) + dtu * Bs[t * 16 + n];
  }
  const size_t base = (size_t)(b * NCH + c) * 16 * 2048 + d;
  #pragma unroll
  for (int n = 0; n < 16; ++n) {
    P[base + n * 2048] = __expf(sumdt * a[n]);
    S[base + n * 2048] = h[n];
  }
}

// ---------------- scan phase B: combine chunk states (in-place into P) ----------------
__global__ __launch_bounds__(256) void k_scan_comb(
    float* __restrict__ P, const float* __restrict__ S)
{
  int idx = blockIdx.x * 256 + threadIdx.x;
  int d = idx & 2047;
  int n = (idx >> 11) & 15;
  int b = idx >> 15;
  float H = 0.f;
  for (int c = 0; c < NCH - 1; ++c) {
    size_t off = ((size_t)(b * NCH + c) * 16 + n) * 2048 + d;
    H = P[off] * H + S[off];
    P[off] = H;
  }
}

// ---------------- scan phase C: seeded local scan -> y, gate ----------------
__global__ __launch_bounds__(256) void k_scan_y(
    const _Float16* __restrict__ dt, const _Float16* __restrict__ u,
    const _Float16* __restrict__ zs, const float* __restrict__ xdbl,
    const float* __restrict__ A_log, const float* __restrict__ Hbuf,
    const float* __restrict__ Dv, _Float16* __restrict__ ys)
{
  const int tid = threadIdx.x;
  const int d = blockIdx.x * 256 + tid;
  const int c = blockIdx.y;
  const int b = blockIdx.z;
  const int row0 = b * 1024 + c * TC;
  __shared__ float Bs[TC * 16];
  __shared__ float Cs[TC * 16];
  for (int i = tid; i < TC * 16; i += 256) {
    int t = i >> 4, n = i & 15;
    Bs[i] = xdbl[(size_t)(row0 + t) * 128 + 64 + n];
    Cs[i] = xdbl[(size_t)(row0 + t) * 128 + 80 + n];
  }
  float a[16];
  #pragma unroll
  for (int n = 0; n < 16; ++n) a[n] = -__expf(A_log[d * 16 + n]);
  float h[16];
  if (c == 0) {
    #pragma unroll
    for (int n = 0; n < 16; ++n) h[n] = 0.f;
  } else {
    const size_t hb = (size_t)(b * NCH + (c - 1)) * 16 * 2048 + d;
    #pragma unroll
    for (int n = 0; n < 16; ++n) h[n] = Hbuf[hb + n * 2048];
  }
  const float Dd = Dv[d];
  __syncthreads();
  for (int t = 0; t < TC; ++t) {
    const int row = row0 + t;
    float dtv = (float)dt[(size_t)row * 2048 + d];
    float uv  = (float)u[(size_t)row * 2048 + d];
    float zv  = (float)zs[(size_t)row * 2048 + d];
    float dtu = dtv * uv;
    float y = uv * Dd;
    #pragma unroll
    for (int n = 0; n < 16; ++n) {
      h[n] = h[n] * __expf(dtv * a[n]) + dtu * Bs[t * 16 + n];
      y = fmaf(h[n], Cs[t * 16 + n], y);
    }
    ys[(size_t)row * 2048 + d] = (_Float16)(y * zv);
  }
}

// ---------------- residual + G4-reduce + LayerNorm + LeakyReLU ----------------
__global__ __launch_bounds__(256) void k_resid_ln(
    const float* __restrict__ x, const float* __restrict__ yp,
    const float* __restrict__ gamma, const float* __restrict__ beta,
    float* __restrict__ out)
{
  int row = blockIdx.x;
  int tid = threadIdx.x;
  const int PL = 4096 * 1024;
  float v[4];
  float s = 0.f, s2 = 0.f;
  #pragma unroll
  for (int i = 0; i < 4; ++i) {
    int c = tid + i * 256;
    size_t off = (size_t)row * 1024 + c;
    float h = x[off] + yp[off] + yp[off + PL];
    v[i] = h; s += h; s2 += h * h;
  }
  #pragma unroll
  for (int off = 32; off > 0; off >>= 1) {
    s  += __shfl_down(s, off, 64);
    s2 += __shfl_down(s2, off, 64);
  }
  __shared__ float rs[4], rs2[4];
  int wv = tid >> 6, ln = tid & 63;
  if (ln == 0) { rs[wv] = s; rs2[wv] = s2; }
  __syncthreads();
  if (tid == 0) {
    float a = 0.f, b2 = 0.f;
    #pragma unroll
    for (int i = 0; i < 4; ++i) { a += rs[i]; b2 += rs2[i]; }
    rs[0] = a; rs2[0] = b2;
  }
  __syncthreads();
  float mu  = rs[0] * (1.f / 1024.f);
  float var = rs2[0] * (1.f / 1024.f) - mu * mu;
  float inv = rsqrtf(var + 1e-5f);
  #pragma unroll
  for (int i = 0; i < 4; ++i) {
    int c = tid + i * 256;
    float hn = (v[i] - mu) * inv * gamma[c] + beta[c];
    out[(size_t)row * 1024 + c] = hn >= 0.f ? hn : 0.01f * hn;
  }
}

extern "C" void kernel_launch(void* const* d_in, const int* in_sizes, int n_in,
                              void* d_out, int out_size, void* d_ws, size_t ws_size,
                              hipStream_t stream)
{
  const float* x     = (const float*)d_in[0];
  const float* W_in  = (const float*)d_in[1];
  const float* convw = (const float*)d_in[2];
  const float* convb = (const float*)d_in[3];
  const float* W_x   = (const float*)d_in[4];
  const float* W_dt  = (const float*)d_in[5];
  const float* b_dt  = (const float*)d_in[6];
  const float* A_log = (const float*)d_in[7];
  const float* Dv    = (const float*)d_in[8];
  const float* W_out = (const float*)d_in[9];
  const float* gamma = (const float*)d_in[10];
  const float* beta  = (const float*)d_in[11];
  float* out = (float*)d_out;

  char* ws = (char*)d_ws;
  const size_t MB = 1ull << 20;
  _Float16* x16   = (_Float16*)(ws + 0 * MB);            // 8 MB   4096x1024   (dies after G1)
  _Float16* WinT  = (_Float16*)(ws + 8 * MB);            // 8 MB   4096x1024   (dies after G1)
  _Float16* xc16  = (_Float16*)(ws + 16 * MB);           // 16 MB  pre-conv xc (dies after conv)
  _Float16* zsil  = (_Float16*)(ws + 32 * MB);           // 16 MB  silu(z)     (dies after scan_y)
  _Float16* xcs   = (_Float16*)(ws + 48 * MB);           // 16 MB  post-conv u
  _Float16* dtb   = (_Float16*)(ws + 64 * MB);           // 16 MB  softplus(dt)
  _Float16* WxT   = (_Float16*)(ws + 80 * MB);           // 0.5 MB 128x2048
  float*    xdbl  = (float*)   (ws + 80 * MB + 512 * 1024);   // 2 MB 4096x128
  _Float16* dtin  = (_Float16*)(ws + 82 * MB + 512 * 1024);   // 0.5 MB 4096x64
  _Float16* WdtT  = (_Float16*)(ws + 83 * MB);           // 0.25 MB 2048x64
  _Float16* WoutT = (_Float16*)(ws + 84 * MB);           // 4 MB   1024x2048
  _Float16* ysb   = (_Float16*)(ws + 88 * MB);           // 16 MB  gated y
  float*    Cpart = (float*)   (ws + 16 * MB);           // 8 MB   reuse xc16 (G2 partials)
  float*    Pb    = (float*)   (ws + 16 * MB);           // 16 MB  reuse xc16 (scan)
  float*    Sb    = (float*)   (ws + 0 * MB);            // 16 MB  reuse x16+WinT (scan)
  float*    yp    = (float*)   (ws + 0 * MB);            // 32 MB  G4 partials (after scan; Sb/Pb dead)

  // 1. cast x to f16
  k_cast16<<<4096 * 1024 / 4 / 256, 256, 0, stream>>>(x, x16, 4096 * 1024 / 4);
  // 2. W_in^T (1024x4096 -> 4096x1024)
  k_transpose16<<<dim3(4096 / 32, 1024 / 32), dim3(32, 8), 0, stream>>>(W_in, WinT, 1024, 4096, 4096);
  // 3. G1: xz = x @ W_in ; xc f16 + silu(z) f16
  k_gemm_bt<3><<<dim3(32, 32), 256, 0, stream>>>(x16, WinT, nullptr, xc16, zsil, nullptr, 4096, 4096, 1024);
  // 4. causal conv + SiLU
  k_conv_silu<<<4096 * 2048 / 256, 256, 0, stream>>>(xc16, convw, convb, xcs);
  // 5. W_x^T padded to 128 rows
  k_transpose16<<<dim3(128 / 32, 2048 / 32), dim3(32, 8), 0, stream>>>(W_x, WxT, 2048, 96, 128);
  // 6. G2 split-K x4: partials then reduce -> xdbl f32, dtin f16
  k_gemm_bt<4><<<dim3(1, 32, 4), 256, 0, stream>>>(xcs, WxT, Cpart, nullptr, nullptr, nullptr, 4096, 128, 2048);
  k_red4<<<4096 * 128 / 256, 256, 0, stream>>>(Cpart, xdbl, dtin);
  // 7. W_dt^T
  k_transpose16<<<dim3(2048 / 32, 64 / 32), dim3(32, 8), 0, stream>>>(W_dt, WdtT, 64, 2048, 2048);
  // 8. G3: dt = softplus(dtin @ W_dt + b_dt)   (K=64 -> single K-iter)
  k_gemm_bt<2><<<dim3(16, 32), 256, 0, stream>>>(dtin, WdtT, nullptr, nullptr, dtb, b_dt, 4096, 2048, 64);
  // 9. chunked selective scan
  k_scan_part<<<dim3(8, NCH, 4), 256, 0, stream>>>(dtb, xcs, xdbl, A_log, Pb, Sb);
  k_scan_comb<<<4 * 16 * 2048 / 256, 256, 0, stream>>>(Pb, Sb);
  k_scan_y<<<dim3(8, NCH, 4), 256, 0, stream>>>(dtb, xcs, zsil, xdbl, A_log, Pb, Dv, ysb);
  // 10. W_out^T
  k_transpose16<<<dim3(1024 / 32, 2048 / 32), dim3(32, 8), 0, stream>>>(W_out, WoutT, 2048, 1024, 1024);
  // 11. G4 split-K x2: partials (reduced inside resid_ln)
  k_gemm_bt<4><<<dim3(8, 32, 2), 256, 0, stream>>>(ysb, WoutT, yp, nullptr, nullptr, nullptr, 4096, 1024, 2048);
  // 12. residual + G4-reduce + LN + LeakyReLU
  k_resid_ln<<<4096, 256, 0, stream>>>(x, yp, gamma, beta, out);
}